// Round 2
// baseline (235.871 us; speedup 1.0000x reference)
//
#include <hip/hip_runtime.h>
#include <hip/hip_bf16.h>

#define B_    8
#define CIN   64
#define COUT  64
#define RN_   4
#define H_    128
#define W_    128
#define HW_   (H_ * W_)
#define BN_EPS 1e-5f

typedef short v8s __attribute__((ext_vector_type(8)));
typedef float v4f __attribute__((ext_vector_type(4)));

__device__ __forceinline__ unsigned short f2bf(float f) {
    unsigned int u = __float_as_uint(f);
    u += 0x7FFFu + ((u >> 16) & 1u);       // round-to-nearest-even
    return (unsigned short)(u >> 16);
}

// ---------------------------------------------------------------------------
// x fp32 [b][c][h][w] -> xT bf16 [b][h][w][c]   (channel-innermost for b128 LDS)
// ---------------------------------------------------------------------------
__global__ __launch_bounds__(256) void xpose_x(const float* __restrict__ x,
                                               unsigned short* __restrict__ xT) {
    const int b = blockIdx.y, h = blockIdx.x;
    __shared__ float tile[CIN * 129];                 // +1 pad: conflict-free
    const float* xp = x + (size_t)b * CIN * HW_ + (size_t)h * W_;
    for (int idx = threadIdx.x; idx < CIN * W_; idx += 256) {
        const int c = idx >> 7, w = idx & 127;
        tile[c * 129 + w] = xp[(size_t)c * HW_ + w];
    }
    __syncthreads();
    unsigned short* op = xT + ((size_t)b * H_ + h) * (W_ * CIN);
    for (int idx = threadIdx.x; idx < (W_ * CIN) / 8; idx += 256) {
        const int w = idx >> 3, c0 = (idx & 7) << 3;
        int4 v;
        v.x = f2bf(tile[(c0 + 0) * 129 + w]) | ((unsigned)f2bf(tile[(c0 + 1) * 129 + w]) << 16);
        v.y = f2bf(tile[(c0 + 2) * 129 + w]) | ((unsigned)f2bf(tile[(c0 + 3) * 129 + w]) << 16);
        v.z = f2bf(tile[(c0 + 4) * 129 + w]) | ((unsigned)f2bf(tile[(c0 + 5) * 129 + w]) << 16);
        v.w = f2bf(tile[(c0 + 6) * 129 + w]) | ((unsigned)f2bf(tile[(c0 + 7) * 129 + w]) << 16);
        *(int4*)(op + (w << 6) + c0) = v;
    }
}

// ---------------------------------------------------------------------------
// kernel fp32 [b][r][o][c][t] -> kT bf16 [b][r][t][o][c]  (A-tiles contiguous)
// ---------------------------------------------------------------------------
__global__ __launch_bounds__(256) void xpose_k(const float* __restrict__ kr,
                                               unsigned short* __restrict__ kT) {
    const int idx = blockIdx.x * 256 + threadIdx.x;   // 1,179,648 total, exact grid
    const int c = idx & 63;
    const int o = (idx >> 6) & 63;
    const int brt = idx >> 12;                        // br*9 + t
    const int t = brt % 9, br = brt / 9;
    kT[idx] = f2bf(kr[(((size_t)br * 64 + o) * 64 + c) * 9 + t]);
}

// ---------------------------------------------------------------------------
// mask logits conv (fp32) + softmax over regions -> masks (= output #2)
// ---------------------------------------------------------------------------
__global__ __launch_bounds__(128) void mask_kernel(const float* __restrict__ x,
                                                   const float* __restrict__ mw,
                                                   const float* __restrict__ mb,
                                                   float* __restrict__ masks) {
    const int b = blockIdx.y, h = blockIdx.x, w = threadIdx.x;
    // repack mask_w: [(c*3+kh)*4 + r]*3 + kw  -> per (c,dh) 12 contiguous floats
    __shared__ float mws2[CIN * 3 * RN_ * 3];
    for (int i = threadIdx.x; i < CIN * 9 * RN_; i += 128) {
        const int r = i / 576, rem = i % 576, c = rem / 9, t = rem % 9;
        mws2[((c * 3 + t / 3) * 4 + r) * 3 + (t % 3)] = mw[i];
    }
    __syncthreads();
    float lg0 = mb[0], lg1 = mb[1], lg2 = mb[2], lg3 = mb[3];
    const float* xb = x + (size_t)b * CIN * HW_;
    #pragma unroll
    for (int dh = -1; dh <= 1; dh++) {
        const int hh = h + dh;
        if (hh < 0 || hh >= H_) continue;
        for (int c = 0; c < CIN; c++) {
            const float* row = xb + ((size_t)c * H_ + hh) * W_;
            const float xm1 = (w >= 1) ? row[w - 1] : 0.f;
            const float x0  = row[w];
            const float xp1 = (w < W_ - 1) ? row[w + 1] : 0.f;
            const float4* p = (const float4*)&mws2[(c * 3 + dh + 1) * 12];
            const float4 q0 = p[0], q1 = p[1], q2 = p[2];
            lg0 += q0.x * xm1 + q0.y * x0 + q0.z * xp1;
            lg1 += q0.w * xm1 + q1.x * x0 + q1.y * xp1;
            lg2 += q1.z * xm1 + q1.w * x0 + q2.x * xp1;
            lg3 += q2.y * xm1 + q2.z * x0 + q2.w * xp1;
        }
    }
    const float mx = fmaxf(fmaxf(lg0, lg1), fmaxf(lg2, lg3));
    const float e0 = __expf(lg0 - mx), e1 = __expf(lg1 - mx);
    const float e2 = __expf(lg2 - mx), e3 = __expf(lg3 - mx);
    const float inv = 1.f / (e0 + e1 + e2 + e3);
    float* mp = masks + (size_t)b * RN_ * HW_ + (size_t)h * W_ + w;
    mp[0] = e0 * inv; mp[HW_] = e1 * inv; mp[2 * HW_] = e2 * inv; mp[3 * HW_] = e3 * inv;
}

// ---------------------------------------------------------------------------
// fused dynamic grouped conv + mask-weighted region sum + BN + ReLU
// block: (h-pair, w-half, b), 128 threads = 2 waves, wave tile 64(M) x 64(N)
// ---------------------------------------------------------------------------
#define WPAD     72                      // channel pitch in LDS (36 dw = 4 mod 32)
#define XS_W     66                      // 64 + 2 halo columns
#define AS_ELEMS (COUT * WPAD)           // 4608
#define XS_ELEMS (4 * XS_W * WPAD)       // 19008

__global__ __launch_bounds__(128, 1) void main_conv(
        const unsigned short* __restrict__ xT,
        const unsigned short* __restrict__ kT,
        const float* __restrict__ masks,
        const float* __restrict__ bn_gamma, const float* __restrict__ bn_beta,
        const float* __restrict__ bn_mean,  const float* __restrict__ bn_var,
        float* __restrict__ outp) {
    __shared__ unsigned short xs[XS_ELEMS];
    __shared__ unsigned short as[2 * AS_ELEMS];
    __shared__ float masks_s[RN_ * 128];
    __shared__ float scale_s[COUT];
    __shared__ float shift_s[COUT];

    const int tid = threadIdx.x;
    const int b  = blockIdx.z;
    const int w0 = blockIdx.y << 6;           // 0 or 64
    const int h0 = blockIdx.x << 1;           // 0..126
    const int lane = tid & 63, wv = tid >> 6; // wave wv owns output row h0+wv
    const int i = lane & 15, g = lane >> 4;

    // ---- stage x halo tile: rows h0-1..h0+2, cols w0-1..w0+64, 64 ch bf16 ----
    const unsigned short* xb = xT + (size_t)b * (HW_ * CIN);
    #pragma unroll
    for (int row = 0; row < 4; row++) {
        const int h_in = h0 - 1 + row;
        const bool hok = (h_in >= 0) && (h_in < H_);
        for (int idx = tid; idx < XS_W * 8; idx += 128) {
            const int w = idx >> 3, c8 = (idx & 7) << 3;
            const int w_in = w0 - 1 + w;
            int4 v = make_int4(0, 0, 0, 0);
            if (hok && (w_in >= 0) && (w_in < W_))
                v = *(const int4*)(xb + ((h_in * W_ + w_in) << 6) + c8);
            *(int4*)(&xs[(row * XS_W + w) * WPAD + c8]) = v;
        }
    }
    // ---- stage masks for this tile: [r][row*64+wl] ----
    #pragma unroll
    for (int q = 0; q < 4; q++) {
        const int idx = q * 128 + tid;
        const int r = idx >> 7, n = idx & 127;
        masks_s[idx] =
            masks[(((size_t)b * RN_ + r) * H_ + (h0 + (n >> 6))) * W_ + w0 + (n & 63)];
    }
    if (tid < COUT) {
        const float sc = bn_gamma[tid] * rsqrtf(bn_var[tid] + BN_EPS);
        scale_s[tid] = sc;
        shift_s[tid] = bn_beta[tid] - bn_mean[tid] * sc;
    }

    // per-lane B-fragment base addresses (tap center, ks=0)
    int bbase[4];
    #pragma unroll
    for (int fn = 0; fn < 4; fn++)
        bbase[fn] = ((wv + 1) * XS_W + fn * 16 + i + 1) * WPAD + g * 8;

    v4f y_acc[4][4], o_acc[4][4];
    #pragma unroll
    for (int fm = 0; fm < 4; fm++)
        #pragma unroll
        for (int fn = 0; fn < 4; fn++) {
            y_acc[fm][fn] = (v4f){0.f, 0.f, 0.f, 0.f};
            o_acc[fm][fn] = (v4f){0.f, 0.f, 0.f, 0.f};
        }

    // A prologue: rt=0 tile (4096 bf16 = 512 chunks of 8) -> 4 int4 regs/thread
    const unsigned short* kb = kT + (size_t)b * (36 * 4096);
    int4 areg[4];
    #pragma unroll
    for (int q = 0; q < 4; q++)
        areg[q] = *(const int4*)(kb + ((q * 128 + tid) << 3));

    __syncthreads();

    int r = 0, tap = 0;
    for (int rt = 0; rt < 36; rt++) {
        const int buf = (rt & 1) * AS_ELEMS;
        // regs -> LDS A buffer: chunk c = q*128+tid covers o = c>>3, ch (c&7)*8..+8
        #pragma unroll
        for (int q = 0; q < 4; q++) {
            const int c = q * 128 + tid;
            *(int4*)(&as[buf + (c >> 3) * WPAD + ((c & 7) << 3)]) = areg[q];
        }
        __syncthreads();
        if (rt < 35) {   // prefetch next A tile while computing this one
            const unsigned short* kn = kb + ((rt + 1) << 12);
            #pragma unroll
            for (int q = 0; q < 4; q++)
                areg[q] = *(const int4*)(kn + ((q * 128 + tid) << 3));
        }
        const int toff = ((tap / 3) * XS_W + (tap % 3)) * WPAD - (XS_W + 1) * WPAD;
        #pragma unroll
        for (int ks = 0; ks < 2; ks++) {
            v8s a[4], bfr[4];
            #pragma unroll
            for (int fm = 0; fm < 4; fm++)
                a[fm] = *(const v8s*)(&as[buf + (fm * 16 + i) * WPAD + ks * 32 + g * 8]);
            #pragma unroll
            for (int fn = 0; fn < 4; fn++)
                bfr[fn] = *(const v8s*)(&xs[bbase[fn] + toff + ks * 32]);
            #pragma unroll
            for (int fm = 0; fm < 4; fm++)
                #pragma unroll
                for (int fn = 0; fn < 4; fn++)
                    y_acc[fm][fn] = __builtin_amdgcn_mfma_f32_16x16x32_bf16(
                        a[fm], bfr[fn], y_acc[fm][fn], 0, 0, 0);
        }
        if (++tap == 9) {   // region done: fold mask weight, reset region acc
            tap = 0;
            #pragma unroll
            for (int fn = 0; fn < 4; fn++) {
                const float mv = masks_s[r * 128 + wv * 64 + fn * 16 + i];
                #pragma unroll
                for (int fm = 0; fm < 4; fm++) {
                    o_acc[fm][fn] += mv * y_acc[fm][fn];
                    y_acc[fm][fn] = (v4f){0.f, 0.f, 0.f, 0.f};
                }
            }
            r++;
        }
    }

    // ---- epilogue: BN + ReLU + store (C/D: n = i, m = g*4+reg within fm*16) ----
    const int h_out = h0 + wv;
    #pragma unroll
    for (int fm = 0; fm < 4; fm++) {
        #pragma unroll
        for (int reg = 0; reg < 4; reg++) {
            const int o = fm * 16 + g * 4 + reg;
            const float sc = scale_s[o], sh = shift_s[o];
            float* rowp = outp + (((size_t)b * COUT + o) * H_ + h_out) * W_ + w0 + i;
            #pragma unroll
            for (int fn = 0; fn < 4; fn++) {
                const float v = o_acc[fm][fn][reg] * sc + sh;
                rowp[fn * 16] = fmaxf(v, 0.f);
            }
        }
    }
}

// ---------------------------------------------------------------------------
extern "C" void kernel_launch(void* const* d_in, const int* in_sizes, int n_in,
                              void* d_out, int out_size, void* d_ws, size_t ws_size,
                              hipStream_t stream) {
    const float* x     = (const float*)d_in[0];
    const float* kr    = (const float*)d_in[1];
    const float* mw    = (const float*)d_in[2];
    const float* mb    = (const float*)d_in[3];
    const float* gamma = (const float*)d_in[4];
    const float* beta  = (const float*)d_in[5];
    const float* mean  = (const float*)d_in[6];
    const float* var   = (const float*)d_in[7];

    float* outp  = (float*)d_out;
    float* masks = outp + (size_t)B_ * COUT * HW_;          // output #2 region

    unsigned short* xT = (unsigned short*)d_ws;             // 16 MB
    unsigned short* kT = xT + (size_t)B_ * HW_ * CIN;       // +2.25 MB

    hipLaunchKernelGGL(xpose_x, dim3(H_, B_), dim3(256), 0, stream, x, xT);
    hipLaunchKernelGGL(xpose_k, dim3(4608), dim3(256), 0, stream, kr, kT);
    hipLaunchKernelGGL(mask_kernel, dim3(H_, B_), dim3(128), 0, stream, x, mw, mb, masks);
    hipLaunchKernelGGL(main_conv, dim3(H_ / 2, 2, B_), dim3(128), 0, stream,
                       xT, kT, masks, gamma, beta, mean, var, outp);
}